// Round 3
// baseline (382.112 us; speedup 1.0000x reference)
//
#include <hip/hip_runtime.h>

#define CC 8
#define HH 256
#define WW 512
#define KK 9
#define SEGW 256   // pixels per block (half row)
#define XF 272     // LDS floats per channel row: covers w in [seg*256-8, seg*256+264)

__global__ __launch_bounds__(256, 4) void dynfilter_kernel(
    const float* __restrict__ x,
    const float* __restrict__ filt,
    const float* __restrict__ fbias,
    float* __restrict__ out)
{
    __shared__ __align__(16) float xs[2][CC][XF];

    const int tid = threadIdx.x;
    const int bid = blockIdx.x;      // 1024 = n(2) * h(256) * seg(2)
    const int seg = bid & 1;
    const int h   = (bid >> 1) & 255;
    const int n   = bid >> 9;

    const int pxg = tid & 63;        // 64 pixel-groups per wave (4 px each)
    const int cp  = tid >> 6;        // wave = one channel-pair (2 ch)
    const int w0  = seg * SEGW + (pxg << 2);
    const int c0  = cp << 1;

    // staging role: 8 groups of 32 lanes, one channel each
    const int lane32 = tid & 31;
    const int cstage = tid >> 5;
    const float* xrowbase = x + ((size_t)(n * CC + cstage)) * (HH * WW)
                              + (seg * SEGW - 8);
    const int wbase = seg * SEGW - 8;

    float acc[2][4];
    {
        const float4 fb = *(const float4*)(fbias + ((size_t)(n * HH + h)) * WW + w0);
        #pragma unroll
        for (int cc = 0; cc < 2; ++cc) {
            acc[cc][0] = fb.x; acc[cc][1] = fb.y; acc[cc][2] = fb.z; acc[cc][3] = fb.w;
        }
    }

    float4 xv[3];
    // issue staging loads for row hh into regs (zero for OOB)
    auto issue_stage = [&](int hh) {
        const bool rowok = (unsigned)hh < (unsigned)HH;
        const float* src = xrowbase + (size_t)hh * WW;
        #pragma unroll
        for (int r = 0; r < 3; ++r) {
            const int k = lane32 + (r << 5);
            const int wg = wbase + (k << 2);
            xv[r] = make_float4(0.f, 0.f, 0.f, 0.f);
            if (k < 68 && rowok && (unsigned)wg < (unsigned)WW)
                xv[r] = *(const float4*)(src + (k << 2));
        }
    };
    auto store_stage = [&](int buf) {
        #pragma unroll
        for (int r = 0; r < 3; ++r) {
            const int k = lane32 + (r << 5);
            if (k < 68) *(float4*)&xs[buf][cstage][k << 2] = xv[r];
        }
    };

    // prologue: stage row h-4 into buffer 0
    issue_stage(h - 4);
    store_stage(0);
    __syncthreads();

    const size_t HW = (size_t)HH * WW;
    const float* fbase = filt + ((size_t)(n * 81) * HH + h) * WW + w0;

    #pragma unroll
    for (int i = 0; i < KK; ++i) {
        // 1) filter taps for tap-row i: 9 coalesced float4 loads (1 KB/wave each)
        float4 fr[KK];
        #pragma unroll
        for (int j = 0; j < KK; ++j)
            fr[j] = *(const float4*)(fbase + (size_t)(i * KK + j) * HW);

        // 2) issue next x-row staging loads (stay in flight during compute)
        if (i < KK - 1) issue_stage(h - 4 + i + 1);

        // 3) compute from current buffer
        #pragma unroll
        for (int cc = 0; cc < 2; ++cc) {
            const float* xr = &xs[i & 1][c0 + cc][(pxg << 2) + 4]; // = x[w0-4 ...]
            float xf[12];
            *(float4*)&xf[0] = *(const float4*)&xr[0];
            *(float4*)&xf[4] = *(const float4*)&xr[4];
            *(float4*)&xf[8] = *(const float4*)&xr[8];
            #pragma unroll
            for (int j = 0; j < KK; ++j) {
                acc[cc][0] = fmaf(fr[j].x, xf[j],     acc[cc][0]);
                acc[cc][1] = fmaf(fr[j].y, xf[j + 1], acc[cc][1]);
                acc[cc][2] = fmaf(fr[j].z, xf[j + 2], acc[cc][2]);
                acc[cc][3] = fmaf(fr[j].w, xf[j + 3], acc[cc][3]);
            }
        }

        // 4) store staged row into the other buffer, single barrier per iter
        if (i < KK - 1) store_stage((i + 1) & 1);
        __syncthreads();
    }

    #pragma unroll
    for (int cc = 0; cc < 2; ++cc) {
        *(float4*)(out + ((size_t)(n * CC + c0 + cc) * HH + h) * WW + w0) =
            make_float4(acc[cc][0], acc[cc][1], acc[cc][2], acc[cc][3]);
    }
}

extern "C" void kernel_launch(void* const* d_in, const int* in_sizes, int n_in,
                              void* d_out, int out_size, void* d_ws, size_t ws_size,
                              hipStream_t stream) {
    const float* x  = (const float*)d_in[0];
    const float* f  = (const float*)d_in[1];
    const float* fb = (const float*)d_in[2];
    float* o = (float*)d_out;
    hipLaunchKernelGGL(dynfilter_kernel, dim3(2 * HH * 2), dim3(256), 0, stream,
                       x, f, fb, o);
}